// Round 12
// baseline (584.801 us; speedup 1.0000x reference)
//
#include <hip/hip_runtime.h>
#include <hip/hip_bf16.h>

// TLSTM forecaster. R12 = R11 + wave specialization: 1024 thr/block, 16 waves.
//  waves 0-7  (grp 0): L0 chain  [gates(t) in I1, update(t) in I2, staging]
//  waves 8-15 (grp 1): L1 chain  [gates(t-1) in I1, update(t-1) in I2]
// Same dataflow/barriers as R11's lagged pipeline; per-SIMD issue work is
// unchanged but waves/SIMD doubles 2->4 (LDS caps us at 1 block/CU; this is
// the only way to add latency-hiding). Frag-order WB0 in LDS, wf1+bwd regs,
// exp2-prescaled trans, 3-slot dm ring, coalesced merged prologue.
// B=4096, L=64, D=16, H=128, NL=2. Gate order [i,o,c] (f-gate dead).
// Scales: i,o,Wt: -log2(e); c,Wd: +2*log2(e)

typedef __bf16 bf16x8 __attribute__((ext_vector_type(8)));
typedef float  f32x4  __attribute__((ext_vector_type(4)));

__device__ __forceinline__ f32x4 mfma16(bf16x8 a, bf16x8 b, f32x4 c) {
  return __builtin_amdgcn_mfma_f32_16x16x32_bf16(a, b, c, 0, 0, 0);
}

#if __has_builtin(__builtin_amdgcn_exp2f)
__device__ __forceinline__ float fexp2(float x) { return __builtin_amdgcn_exp2f(x); }
#else
__device__ __forceinline__ float fexp2(float x) { return exp2f(x); }
#endif
#if __has_builtin(__builtin_amdgcn_rcpf)
__device__ __forceinline__ float frcp(float x) { return __builtin_amdgcn_rcpf(x); }
#else
__device__ __forceinline__ float frcp(float x) { return __fdividef(1.f, x); }
#endif
__device__ __forceinline__ float sigmE(float u) { return frcp(1.f + fexp2(u)); }
__device__ __forceinline__ float tanhE(float u) {
  return __fmaf_rn(-2.f, frcp(1.f + fexp2(u)), 1.f);
}
#define SCL_S (-1.44269504f)
#define SCL_T (2.88539008f)

// ---------------- ws layout (bytes) ----------------
#define OFF_BWD0 122880
#define OFF_BT1  155648
#define OFF_BWD1 352256
#define OFF_BZ0  385024

// ---------------- dynamic LDS layout (bytes) ----------------
#define S_WB0   0        // frag-order, 122880
#define S_AH    122880   // [2][16][40] bf16 = 2560 (cols 16..31 zero)
#define S_A0H   125440   // [16][136] bf16 = 4352 (h0)
#define S_A1H   129792   // [16][136] bf16 = 4352 (h1)
#define S_AT0   134144   // [16][136] bf16 = 4352
#define S_AT1   138496   // [16][136] bf16 = 4352
#define S_DM    142848   // [3][2][16] f32 = 384 (ring)
#define S_LAST  143232   // [16] int
#define S_TOTAL 143296
// head-stage aliases (over WB0):
#define S_STATE 0
#define S_A1L   9216
#define S_REDS  17408
#define S_REDQ  18432

__device__ __forceinline__ int bt0f_off(int n, int k) {
  int g = n >> 7, w = (n >> 4) & 7, c = n & 15;
  int kk = k >> 5, q = (k >> 3) & 3, j = k & 7;
  return ((w * 3 + g) * 5 + kk) * 512 + (q * 16 + c) * 8 + j;
}

// Merged prologue, n-fastest mapping (coalesced reads everywhere).
__global__ void tlstm_prep(const float* __restrict__ Wp, const float* __restrict__ bp,
                           const float* __restrict__ Wx, const float* __restrict__ bx,
                           const float* __restrict__ Uh, const float* __restrict__ Wd,
                           __bf16* __restrict__ BT0f, __bf16* __restrict__ BWd0,
                           __bf16* __restrict__ BT1, __bf16* __restrict__ BWd1,
                           float* __restrict__ bz0) {
  if (blockIdx.x < 26) {
    int idx = blockIdx.x * 256 + threadIdx.x;          // (n fastest)
    if (idx >= 384 * 17) return;
    int kk = idx / 384, n = idx - kk * 384;
    int npr = n & 127, g = n >> 7, gs = g + 1;         // src gates 1,2,3 = i,o,c
    float sg = (g == 2) ? SCL_T : SCL_S;
    const float* wxg = Wx + (gs * 128) * 128 + npr;    // Wx[0][gs][h][npr]
    if (kk < 16) {
      const float* wprow = Wp + kk * 128;
      float s = 0.f;
      for (int h = 0; h < 128; ++h) s += wprow[h] * wxg[h * 128];
      BT0f[bt0f_off(n, kk)] = (__bf16)(s * sg);
    } else {
      float s = bx[gs * 128 + npr];
      for (int h = 0; h < 128; ++h) s += bp[h] * wxg[h * 128];
      bz0[n] = s * sg;
      for (int k2 = 16; k2 < 32; ++k2) BT0f[bt0f_off(n, k2)] = (__bf16)0.f;
    }
    return;
  }
  int e = (blockIdx.x - 26) * 256 + threadIdx.x;
  if (e < 49152) {                                  // BT0f Uh0, n fastest
    int k = e / 384, n = e - k * 384;
    int npr = n & 127, g = n >> 7, gs = g + 1;
    float sg = (g == 2) ? SCL_T : SCL_S;
    BT0f[bt0f_off(n, k + 32)] = (__bf16)(Uh[(gs * 128 + k) * 128 + npr] * sg);
  } else if (e < 65536) {                           // BWd0
    int e2 = e - 49152; int k = e2 >> 7, n = e2 & 127;
    BWd0[n * 128 + k] = (__bf16)(Wd[k * 128 + n] * SCL_T);
  } else if (e < 163840) {                          // BT1
    int e2 = e - 65536; int k = e2 / 384, n = e2 - k * 384;
    int npr = n & 127, g = n >> 7, gs = g + 1;
    float sg = (g == 2) ? SCL_T : SCL_S;
    float v = (k < 128) ? Wx[((4 + gs) * 128 + k) * 128 + npr]
                        : Uh[((4 + gs) * 128 + (k - 128)) * 128 + npr];
    BT1[n * 256 + k] = (__bf16)(v * sg);
  } else if (e < 180224) {                          // BWd1
    int e2 = e - 163840; int k = e2 >> 7, n = e2 & 127;
    BWd1[n * 128 + k] = (__bf16)(Wd[(128 + k) * 128 + n] * SCL_T);
  }
}

__global__ __launch_bounds__(1024, 1) void tlstm_main(
    const float* __restrict__ hist, const float* __restrict__ hmask,
    const __bf16* __restrict__ BT0f, const __bf16* __restrict__ BWd0,
    const __bf16* __restrict__ BT1, const __bf16* __restrict__ BWd1,
    const float* __restrict__ bz0, const float* __restrict__ bx,
    const float* __restrict__ bd, const float* __restrict__ Wt,
    const float* __restrict__ bt, const float* __restrict__ lng,
    const float* __restrict__ lnb, const float* __restrict__ W1,
    const float* __restrict__ b1, const float* __restrict__ W2,
    const float* __restrict__ b2, float* __restrict__ out) {
  extern __shared__ __align__(16) char smem[];
  __bf16* WB0 = (__bf16*)(smem + S_WB0);
  __bf16 (*AH)[16][40]  = (__bf16(*)[16][40])(smem + S_AH);
  __bf16 (*A0H)[136]    = (__bf16(*)[136])(smem + S_A0H);
  __bf16 (*A1H)[136]    = (__bf16(*)[136])(smem + S_A1H);
  __bf16 (*AT0)[136]    = (__bf16(*)[136])(smem + S_AT0);
  __bf16 (*AT1)[136]    = (__bf16(*)[136])(smem + S_AT1);
  float (*dmL)[2][16]   = (float(*)[2][16])(smem + S_DM);   // [3 slots][d/m][row]
  int*   lastL          = (int*)(smem + S_LAST);
  float (*stateL)[144]  = (float(*)[144])(smem + S_STATE);
  float (*a1L)[128]     = (float(*)[128])(smem + S_A1L);
  float (*redS)[16]     = (float(*)[16])(smem + S_REDS);
  float (*redQ)[16]     = (float(*)[16])(smem + S_REDQ);

  const int tid  = threadIdx.x;
  const int grp  = tid >> 9;         // 0: L0 chain (waves 0-7), 1: L1 chain (8-15)
  const int w8   = (tid >> 6) & 7;   // wave index within group
  const int lane = tid & 63;
  const int q    = lane >> 4;
  const int c16  = lane & 15;
  const int q8   = q * 8;
  const int b0   = blockIdx.x * 16;
  const int nc   = w8 * 16 + c16;    // owned N-column (0..127)

  // ---- one-time init ----
  for (int i = tid * 8; i < 61440; i += 8192)          // BT0f -> LDS
    *(bf16x8*)(WB0 + i) = *(const bf16x8*)(BT0f + i);
  {
    __bf16* z = (__bf16*)(smem + S_AH);                // zero AH+A0H+A1H
    for (int i = tid; i < 5632; i += 1024) z[i] = (__bf16)0.f;
  }
  if (tid < 16) {
    float s = 0.f;
    for (int t = 0; t < 64; ++t) s += hmask[(b0 + tid) * 64 + t];
    s = fminf(fmaxf(s, 1.f), 64.f);
    lastL[tid] = (int)s - 1;
  }

  // per-wave constants (layer = grp; biases prescaled)
  const int lo = grp * 128;
  float bzr[3];
  if (grp == 0) {
#pragma unroll
    for (int g = 0; g < 3; ++g) bzr[g] = bz0[g * 128 + nc];   // scaled in prep
  } else {
#pragma unroll
    for (int g = 0; g < 3; ++g) {
      float sg = (g == 2) ? SCL_T : SCL_S;
      bzr[g] = bx[(5 + g) * 128 + nc] * sg;
    }
  }
  const float bdr = bd[lo + nc] * SCL_T;
  const float wtr = Wt[lo + nc] * SCL_S;
  const float btr = bt[lo + nc] * SCL_S;

  // weights: grp0 uses WB0 (LDS) + bwd(BWd0); grp1 uses wf1(regs) + bwd(BWd1)
  int offW[3];
  bf16x8 wf1[24], bwd[4];
  if (grp == 0) {
#pragma unroll
    for (int g = 0; g < 3; ++g) offW[g] = ((w8 * 3 + g) * 5) * 512 + lane * 8;
#pragma unroll
    for (int kk = 0; kk < 4; ++kk)
      bwd[kk] = *(const bf16x8*)(BWd0 + nc * 128 + q8 + kk * 32);
  } else {
#pragma unroll
    for (int g = 0; g < 3; ++g)
#pragma unroll
      for (int kk = 0; kk < 8; ++kk)
        wf1[g * 8 + kk] = *(const bf16x8*)(BT1 + (g * 128 + nc) * 256 + kk * 32 + q8);
#pragma unroll
    for (int kk = 0; kk < 4; ++kk)
      bwd[kk] = *(const bf16x8*)(BWd1 + nc * 128 + q8 + kk * 32);
  }

  float hr[4] = {}, cr[4] = {}, encr[4] = {};

  __syncthreads();   // init complete

  int lrow[4];
#pragma unroll
  for (int r = 0; r < 4; ++r) lrow[r] = lastL[q * 4 + r];

  const int srow = (tid >> 4) & 15, scol = tid & 15;   // staging/head map (tid<256)
  const float* histrow = hist + (long)(b0 + srow) * 1024 + scol;
  const float* hmrow   = hmask + (long)(b0 + srow) * 64;

  // stage t=0 into dm slot 0 / AH slot 0; prefetch t=1
  float hv = 0.f, mv = 0.f;
  if (tid < 256) {
    float v0 = histrow[0];
    AH[0][srow][scol] = (__bf16)v0;
    if (scol == 5)
      dmL[0][0][srow] = __fdividef(1.f, __logf(2.7182818284590452f + fmaxf(v0, 0.f)));
    if (scol == 0) dmL[0][1][srow] = hmrow[0];
    hv = histrow[16];
    mv = hmrow[1];
  }
  __syncthreads();

  // lagged pipeline: iter t = L0(t) by grp0  ||  L1(t-1) by grp1.
  for (int t = 0; t <= 64; ++t) {
    const int p = t & 1, pn = p ^ 1;
    const int sp = t % 3, sm = (t + 2) % 3, sn = (t + 1) % 3;

    // ================= I1: gate GEMMs =================
    float otl[4];
    if (grp == 0) {
      if (t < 64) {   // L0 gates(t): z = [hist|0|h0(t-1)] @ WB0f (K=160, LDS)
        f32x4 acc[3];
#pragma unroll
        for (int g = 0; g < 3; ++g) acc[g] = (f32x4){bzr[g], bzr[g], bzr[g], bzr[g]};
        {
          bf16x8 a = *(const bf16x8*)&AH[p][c16][q8];
#pragma unroll
          for (int g = 0; g < 3; ++g)
            acc[g] = mfma16(a, *(const bf16x8*)(WB0 + offW[g]), acc[g]);
        }
#pragma unroll
        for (int kk = 0; kk < 4; ++kk) {
          bf16x8 a = *(const bf16x8*)&A0H[c16][kk * 32 + q8];
#pragma unroll
          for (int g = 0; g < 3; ++g)
            acc[g] = mfma16(a, *(const bf16x8*)(WB0 + offW[g] + (kk + 1) * 512), acc[g]);
        }
#pragma unroll
        for (int r = 0; r < 4; ++r) {
          float ht = tanhE(acc[2][r]) + sigmE(acc[0][r]);
          otl[r] = sigmE(acc[1][r]);
          AT0[q * 4 + r][nc] = (__bf16)ht;    // htl re-read in I2
        }
      }
    } else {
      if (t > 0) {    // L1 gates(t-1): z = [h0(t-1)|h1(t-2)] @ wf1 (K=256, regs)
        f32x4 acc[3];
#pragma unroll
        for (int g = 0; g < 3; ++g) acc[g] = (f32x4){bzr[g], bzr[g], bzr[g], bzr[g]};
#pragma unroll
        for (int kk = 0; kk < 4; ++kk) {
          bf16x8 a = *(const bf16x8*)&A0H[c16][kk * 32 + q8];
#pragma unroll
          for (int g = 0; g < 3; ++g) acc[g] = mfma16(a, wf1[g * 8 + kk], acc[g]);
        }
#pragma unroll
        for (int kk = 0; kk < 4; ++kk) {
          bf16x8 a = *(const bf16x8*)&A1H[c16][kk * 32 + q8];
#pragma unroll
          for (int g = 0; g < 3; ++g) acc[g] = mfma16(a, wf1[g * 8 + 4 + kk], acc[g]);
        }
#pragma unroll
        for (int r = 0; r < 4; ++r) {
          float ht = tanhE(acc[2][r]) + sigmE(acc[0][r]);
          otl[r] = sigmE(acc[1][r]);
          AT1[q * 4 + r][nc] = (__bf16)ht;    // htl re-read in I2
        }
      }
    }
    __syncthreads();   // B1

    // ================= I2: Wd GEMMs + state updates =================
    if (grp == 0) {
      if (t < 64) {   // L0 update(t) -> h0(t) into A0H
        float drow[4], mrow[4];
#pragma unroll
        for (int r = 0; r < 4; ++r) {
          drow[r] = dmL[sp][0][q * 4 + r];
          mrow[r] = dmL[sp][1][q * 4 + r];
        }
        f32x4 accd = (f32x4){bdr, bdr, bdr, bdr};
#pragma unroll
        for (int kk = 0; kk < 4; ++kk) {
          bf16x8 a = *(const bf16x8*)&AT0[c16][kk * 32 + q8];
          accd = mfma16(a, bwd[kk], accd);
        }
#pragma unroll
        for (int r = 0; r < 4; ++r) {
          float htl   = (float)AT0[q * 4 + r][nc];
          float hs    = tanhE(accd[r]);
          float dgate = sigmE(__fmaf_rn(drow[r], wtr, btr));
          float hstar = __fmaf_rn(hs, dgate - 1.f, htl);
          float cn    = tanhE(SCL_T * __fmaf_rn(otl[r], cr[r], hstar));
          float hn    = otl[r] * tanhE(SCL_T * cn);
          float m     = mrow[r];
          float hl    = __fmaf_rn(m, hn - hr[r], hr[r]);
          float cl    = __fmaf_rn(m, cn - cr[r], cr[r]);
          hr[r] = hl; cr[r] = cl;
          A0H[q * 4 + r][nc] = (__bf16)hl;
        }
      }
      // stage t+1 into AH[pn] / dm slot sn
      if (tid < 256 && t < 63) {
        AH[pn][srow][scol] = (__bf16)hv;
        if (scol == 5)
          dmL[sn][0][srow] = __fdividef(1.f, __logf(2.7182818284590452f + fmaxf(hv, 0.f)));
        if (scol == 0) dmL[sn][1][srow] = mv;
        if (t < 62) { hv = histrow[(t + 2) * 16]; mv = hmrow[t + 2]; }
      }
    } else {
      if (t > 0) {    // L1 update(t-1) -> h1(t-1) into A1H; capture encoded
        float dpre[4], mpre[4];
#pragma unroll
        for (int r = 0; r < 4; ++r) {
          dpre[r] = dmL[sm][0][q * 4 + r];
          mpre[r] = dmL[sm][1][q * 4 + r];
        }
        f32x4 accd = (f32x4){bdr, bdr, bdr, bdr};
#pragma unroll
        for (int kk = 0; kk < 4; ++kk) {
          bf16x8 a = *(const bf16x8*)&AT1[c16][kk * 32 + q8];
          accd = mfma16(a, bwd[kk], accd);
        }
        const int tm1 = t - 1;
#pragma unroll
        for (int r = 0; r < 4; ++r) {
          float htl   = (float)AT1[q * 4 + r][nc];
          float hs    = tanhE(accd[r]);
          float dgate = sigmE(__fmaf_rn(dpre[r], wtr, btr));
          float hstar = __fmaf_rn(hs, dgate - 1.f, htl);
          float cn    = tanhE(SCL_T * __fmaf_rn(otl[r], cr[r], hstar));
          float hn    = otl[r] * tanhE(SCL_T * cn);
          float m     = mpre[r];
          float hl    = __fmaf_rn(m, hn - hr[r], hr[r]);
          float cl    = __fmaf_rn(m, cn - cr[r], cr[r]);
          hr[r] = hl; cr[r] = cl;
          A1H[q * 4 + r][nc] = (__bf16)hl;
          if (tm1 == lrow[r]) encr[r] = hl * m;
        }
      }
    }
    __syncthreads();   // B2
  }

  // ---- decoder head: state = [hist[b,last,:16] | enc128]; LN; FC-ReLU-FC ----
  if (tid < 256)
    stateL[srow][scol] = hist[((long)(b0 + srow) * 64 + lastL[srow]) * 16 + scol];
  if (grp == 1) {
#pragma unroll
    for (int r = 0; r < 4; ++r)
      stateL[q * 4 + r][16 + nc] = encr[r];
  }
  __syncthreads();

  if (tid < 256) {
    float sm2 = 0.f, sq = 0.f;
    for (int k = scol; k < 144; k += 16) {
      float v = stateL[srow][k];
      sm2 += v; sq += v * v;
    }
    redS[srow][scol] = sm2; redQ[srow][scol] = sq;
  }
  __syncthreads();
  if (tid < 16) {
    float sm2 = 0.f, sq = 0.f;
    for (int s2 = 0; s2 < 16; ++s2) { sm2 += redS[tid][s2]; sq += redQ[tid][s2]; }
    float mu  = sm2 * (1.f / 144.f);
    float var = sq * (1.f / 144.f) - mu * mu;
    redS[0][tid] = mu;
    redQ[0][tid] = rsqrtf(var + 1e-5f);
  }
  __syncthreads();
  if (tid < 256) {
    float mu = redS[0][srow], rs = redQ[0][srow];
    for (int k = scol; k < 144; k += 16)
      stateL[srow][k] = (stateL[srow][k] - mu) * rs * lng[k] + lnb[k];
  }
  __syncthreads();
  if (tid < 256) {
    float accw[8];
#pragma unroll
    for (int o = 0; o < 8; ++o) accw[o] = b1[scol + 16 * o];
    for (int k = 0; k < 144; ++k) {
      float sv = stateL[srow][k];
      const float* w = W1 + k * 128 + scol;
#pragma unroll
      for (int o = 0; o < 8; ++o) accw[o] += sv * w[16 * o];
    }
#pragma unroll
    for (int o = 0; o < 8; ++o) a1L[srow][scol + 16 * o] = fmaxf(accw[o], 0.f);
  }
  __syncthreads();
  for (int e = tid; e < 960; e += 1024) {
    int row = e / 60, j = e - row * 60;
    float accv = b2[j];
    for (int k = 0; k < 128; ++k) accv += a1L[row][k] * W2[k * 60 + j];
    accv = (accv != accv) ? 0.f : fminf(fmaxf(accv, -1e4f), 1e4f);  // nan_to_num
    out[(b0 + row) * 60 + j] = accv;
  }
}

extern "C" void kernel_launch(void* const* d_in, const int* in_sizes, int n_in,
                              void* d_out, int out_size, void* d_ws, size_t ws_size,
                              hipStream_t stream) {
  const float* hist  = (const float*)d_in[0];
  const float* hmask = (const float*)d_in[1];
  const float* Wp    = (const float*)d_in[2];
  const float* bp    = (const float*)d_in[3];
  const float* Wx    = (const float*)d_in[4];
  const float* bx    = (const float*)d_in[5];
  const float* Uh    = (const float*)d_in[6];
  const float* Wd    = (const float*)d_in[7];
  const float* bd    = (const float*)d_in[8];
  const float* Wt    = (const float*)d_in[9];
  const float* bt    = (const float*)d_in[10];
  const float* lng   = (const float*)d_in[11];
  const float* lnb   = (const float*)d_in[12];
  const float* W1    = (const float*)d_in[13];
  const float* b1    = (const float*)d_in[14];
  const float* W2    = (const float*)d_in[15];
  const float* b2    = (const float*)d_in[16];
  float* out = (float*)d_out;

  char* ws = (char*)d_ws;
  __bf16* BT0f = (__bf16*)ws;
  __bf16* BWd0 = (__bf16*)(ws + OFF_BWD0);
  __bf16* BT1  = (__bf16*)(ws + OFF_BT1);
  __bf16* BWd1 = (__bf16*)(ws + OFF_BWD1);
  float*  bz0  = (float*)(ws + OFF_BZ0);

  hipFuncSetAttribute((const void*)tlstm_main,
                      hipFuncAttributeMaxDynamicSharedMemorySize, S_TOTAL);

  tlstm_prep<<<730, 256, 0, stream>>>(Wp, bp, Wx, bx, Uh, Wd,
                                      BT0f, BWd0, BT1, BWd1, bz0);
  tlstm_main<<<256, 1024, S_TOTAL, stream>>>(hist, hmask, BT0f, BWd0, BT1, BWd1,
                                             bz0, bx, bd, Wt, bt, lng, lnb,
                                             W1, b1, W2, b2, out);
}

// Round 13
// 294.643 us; speedup vs baseline: 1.9848x; 1.9848x over previous
//
#include <hip/hip_runtime.h>
#include <hip/hip_bf16.h>

// TLSTM forecaster. R13 = R11 (best: 229.5us main) + micro-cleanup:
//  - htl0/htl1 carried in regs across B1 (R11's AT re-read added conflicts;
//    the R10 spill was from A-frag sharing, not these 8 regs)
//  - drow/mrow/dpre/mpre read as float4 (1 ds_read_b128 vs 4 scalar reads)
// Structure locked by R12's lesson: 2 waves/SIMD = 256 regs/wave is the HW
// optimum (4 waves/SIMD -> 128 regs/wave -> weight spill catastrophe).
// Frag-order WB0 in LDS, wf1+bwd in regs (32 frags = 128 AGPR), exp2-
// prescaled trans, 3-slot dm ring, lagged L0/L1 pipeline, 2 barriers/step.
// B=4096, L=64, D=16, H=128, NL=2. Gate order [i,o,c] (f-gate dead).
// Scales: i,o,Wt: -log2(e); c,Wd: +2*log2(e)

typedef __bf16 bf16x8 __attribute__((ext_vector_type(8)));
typedef float  f32x4  __attribute__((ext_vector_type(4)));

__device__ __forceinline__ f32x4 mfma16(bf16x8 a, bf16x8 b, f32x4 c) {
  return __builtin_amdgcn_mfma_f32_16x16x32_bf16(a, b, c, 0, 0, 0);
}

#if __has_builtin(__builtin_amdgcn_exp2f)
__device__ __forceinline__ float fexp2(float x) { return __builtin_amdgcn_exp2f(x); }
#else
__device__ __forceinline__ float fexp2(float x) { return exp2f(x); }
#endif
#if __has_builtin(__builtin_amdgcn_rcpf)
__device__ __forceinline__ float frcp(float x) { return __builtin_amdgcn_rcpf(x); }
#else
__device__ __forceinline__ float frcp(float x) { return __fdividef(1.f, x); }
#endif
__device__ __forceinline__ float sigmE(float u) { return frcp(1.f + fexp2(u)); }
__device__ __forceinline__ float tanhE(float u) {
  return __fmaf_rn(-2.f, frcp(1.f + fexp2(u)), 1.f);
}
#define SCL_S (-1.44269504f)
#define SCL_T (2.88539008f)

// ---------------- ws layout (bytes) ----------------
#define OFF_BWD0 122880
#define OFF_BT1  155648
#define OFF_BWD1 352256
#define OFF_BZ0  385024

// ---------------- dynamic LDS layout (bytes) ----------------
#define S_WB0   0        // frag-order, 122880
#define S_AH    122880   // [2][16][40] bf16 = 2560 (cols 16..31 zero)
#define S_A0H   125440   // [16][136] bf16 = 4352 (h0)
#define S_A1H   129792   // [16][136] bf16 = 4352 (h1)
#define S_AT0   134144   // [16][136] bf16 = 4352
#define S_AT1   138496   // [16][136] bf16 = 4352
#define S_DM    142848   // [3][2][16] f32 = 384 (ring; [slot][d|m][row])
#define S_LAST  143232   // [16] int
#define S_TOTAL 143296
// head-stage aliases (over WB0):
#define S_STATE 0
#define S_A1L   9216
#define S_REDS  17408
#define S_REDQ  18432

__device__ __forceinline__ int bt0f_off(int n, int k) {
  int g = n >> 7, w = (n >> 4) & 7, c = n & 15;
  int kk = k >> 5, q = (k >> 3) & 3, j = k & 7;
  return ((w * 3 + g) * 5 + kk) * 512 + (q * 16 + c) * 8 + j;
}

// Merged prologue, n-fastest mapping (coalesced reads everywhere).
__global__ void tlstm_prep(const float* __restrict__ Wp, const float* __restrict__ bp,
                           const float* __restrict__ Wx, const float* __restrict__ bx,
                           const float* __restrict__ Uh, const float* __restrict__ Wd,
                           __bf16* __restrict__ BT0f, __bf16* __restrict__ BWd0,
                           __bf16* __restrict__ BT1, __bf16* __restrict__ BWd1,
                           float* __restrict__ bz0) {
  if (blockIdx.x < 26) {
    int idx = blockIdx.x * 256 + threadIdx.x;          // (n fastest)
    if (idx >= 384 * 17) return;
    int kk = idx / 384, n = idx - kk * 384;
    int npr = n & 127, g = n >> 7, gs = g + 1;         // src gates 1,2,3 = i,o,c
    float sg = (g == 2) ? SCL_T : SCL_S;
    const float* wxg = Wx + (gs * 128) * 128 + npr;    // Wx[0][gs][h][npr]
    if (kk < 16) {
      const float* wprow = Wp + kk * 128;
      float s = 0.f;
      for (int h = 0; h < 128; ++h) s += wprow[h] * wxg[h * 128];
      BT0f[bt0f_off(n, kk)] = (__bf16)(s * sg);
    } else {
      float s = bx[gs * 128 + npr];
      for (int h = 0; h < 128; ++h) s += bp[h] * wxg[h * 128];
      bz0[n] = s * sg;
      for (int k2 = 16; k2 < 32; ++k2) BT0f[bt0f_off(n, k2)] = (__bf16)0.f;
    }
    return;
  }
  int e = (blockIdx.x - 26) * 256 + threadIdx.x;
  if (e < 49152) {                                  // BT0f Uh0, n fastest
    int k = e / 384, n = e - k * 384;
    int npr = n & 127, g = n >> 7, gs = g + 1;
    float sg = (g == 2) ? SCL_T : SCL_S;
    BT0f[bt0f_off(n, k + 32)] = (__bf16)(Uh[(gs * 128 + k) * 128 + npr] * sg);
  } else if (e < 65536) {                           // BWd0
    int e2 = e - 49152; int k = e2 >> 7, n = e2 & 127;
    BWd0[n * 128 + k] = (__bf16)(Wd[k * 128 + n] * SCL_T);
  } else if (e < 163840) {                          // BT1
    int e2 = e - 65536; int k = e2 / 384, n = e2 - k * 384;
    int npr = n & 127, g = n >> 7, gs = g + 1;
    float sg = (g == 2) ? SCL_T : SCL_S;
    float v = (k < 128) ? Wx[((4 + gs) * 128 + k) * 128 + npr]
                        : Uh[((4 + gs) * 128 + (k - 128)) * 128 + npr];
    BT1[n * 256 + k] = (__bf16)(v * sg);
  } else if (e < 180224) {                          // BWd1
    int e2 = e - 163840; int k = e2 >> 7, n = e2 & 127;
    BWd1[n * 128 + k] = (__bf16)(Wd[(128 + k) * 128 + n] * SCL_T);
  }
}

__global__ __launch_bounds__(512, 1) void tlstm_main(
    const float* __restrict__ hist, const float* __restrict__ hmask,
    const __bf16* __restrict__ BT0f, const __bf16* __restrict__ BWd0,
    const __bf16* __restrict__ BT1, const __bf16* __restrict__ BWd1,
    const float* __restrict__ bz0, const float* __restrict__ bx,
    const float* __restrict__ bd, const float* __restrict__ Wt,
    const float* __restrict__ bt, const float* __restrict__ lng,
    const float* __restrict__ lnb, const float* __restrict__ W1,
    const float* __restrict__ b1, const float* __restrict__ W2,
    const float* __restrict__ b2, float* __restrict__ out) {
  extern __shared__ __align__(16) char smem[];
  __bf16* WB0 = (__bf16*)(smem + S_WB0);
  __bf16 (*AH)[16][40]  = (__bf16(*)[16][40])(smem + S_AH);
  __bf16 (*A0H)[136]    = (__bf16(*)[136])(smem + S_A0H);
  __bf16 (*A1H)[136]    = (__bf16(*)[136])(smem + S_A1H);
  __bf16 (*AT0)[136]    = (__bf16(*)[136])(smem + S_AT0);
  __bf16 (*AT1)[136]    = (__bf16(*)[136])(smem + S_AT1);
  float (*dmL)[2][16]   = (float(*)[2][16])(smem + S_DM);   // [3 slots][d/m][row]
  int*   lastL          = (int*)(smem + S_LAST);
  float (*stateL)[144]  = (float(*)[144])(smem + S_STATE);
  float (*a1L)[128]     = (float(*)[128])(smem + S_A1L);
  float (*redS)[16]     = (float(*)[16])(smem + S_REDS);
  float (*redQ)[16]     = (float(*)[16])(smem + S_REDQ);

  const int tid  = threadIdx.x;
  const int wave = tid >> 6;
  const int lane = tid & 63;
  const int q    = lane >> 4;
  const int c16  = lane & 15;
  const int q8   = q * 8;
  const int b0   = blockIdx.x * 16;
  const int nc   = wave * 16 + c16;  // owned N-column (0..127)

  // ---- one-time init ----
  for (int i = tid * 8; i < 61440; i += 4096)          // BT0f -> LDS (linear copy)
    *(bf16x8*)(WB0 + i) = *(const bf16x8*)(BT0f + i);
  {
    __bf16* z = (__bf16*)(smem + S_AH);                // zero AH+A0H+A1H
    for (int i = tid; i < 5632; i += 512) z[i] = (__bf16)0.f;
  }
  if (tid < 16) {
    float s = 0.f;
    for (int t = 0; t < 64; ++t) s += hmask[(b0 + tid) * 64 + t];
    s = fminf(fmaxf(s, 1.f), 64.f);
    lastL[tid] = (int)s - 1;
  }

  // per-wave constants (biases prescaled)
  float bz0r[3], bz1r[3];
#pragma unroll
  for (int g = 0; g < 3; ++g) {
    float sg = (g == 2) ? SCL_T : SCL_S;
    bz0r[g] = bz0[g * 128 + nc];                 // scaled in prep
    bz1r[g] = bx[(5 + g) * 128 + nc] * sg;
  }
  const float bd0r = bd[nc] * SCL_T,       bd1r = bd[128 + nc] * SCL_T;
  const float wt0r = Wt[nc] * SCL_S,       wt1r = Wt[128 + nc] * SCL_S;
  const float bt0r = bt[nc] * SCL_S,       bt1r = bt[128 + nc] * SCL_S;

  // frag-order WB0 bases: frag(g,kk) at ((wave*3+g)*5+kk)*512 + lane*8
  int offW[3];
#pragma unroll
  for (int g = 0; g < 3; ++g) offW[g] = ((wave * 3 + g) * 5) * 512 + lane * 8;

  // register weights: wf1 (24) + bwd0/1 (8) = 32 frags (proven no-spill)
  bf16x8 wf1[24], bwd0[4], bwd1[4];
#pragma unroll
  for (int g = 0; g < 3; ++g)
#pragma unroll
    for (int kk = 0; kk < 8; ++kk)
      wf1[g * 8 + kk] = *(const bf16x8*)(BT1 + (g * 128 + nc) * 256 + kk * 32 + q8);
#pragma unroll
  for (int kk = 0; kk < 4; ++kk) {
    bwd0[kk] = *(const bf16x8*)(BWd0 + nc * 128 + q8 + kk * 32);
    bwd1[kk] = *(const bf16x8*)(BWd1 + nc * 128 + q8 + kk * 32);
  }

  float h0r[4] = {}, c0r[4] = {}, h1r[4] = {}, c1r[4] = {}, encr[4] = {};

  __syncthreads();   // init complete

  int lrow[4];
#pragma unroll
  for (int r = 0; r < 4; ++r) lrow[r] = lastL[q * 4 + r];

  const int srow = (tid >> 4) & 15, scol = tid & 15;   // staging/head map (tid<256)
  const float* histrow = hist + (long)(b0 + srow) * 1024 + scol;
  const float* hmrow   = hmask + (long)(b0 + srow) * 64;

  // stage t=0 into dm slot 0 / AH slot 0; prefetch t=1
  float hv = 0.f, mv = 0.f;
  if (tid < 256) {
    float v0 = histrow[0];
    AH[0][srow][scol] = (__bf16)v0;
    if (scol == 5)
      dmL[0][0][srow] = __fdividef(1.f, __logf(2.7182818284590452f + fmaxf(v0, 0.f)));
    if (scol == 0) dmL[0][1][srow] = hmrow[0];
    hv = histrow[16];
    mv = hmrow[1];
  }
  __syncthreads();

  // lagged pipeline: iter t runs L0(t) and L1(t-1); t=64 drains L1(63).
  for (int t = 0; t <= 64; ++t) {
    const int p = t & 1, pn = p ^ 1;
    const int sp = t % 3, sm = (t + 2) % 3, sn = (t + 1) % 3;

    // ================= I1: gate GEMMs (independent chains, own loads) =========
    float htl0[4], otl0[4], htl1[4], otl1[4];
    if (t > 0) {    // L1 gates(t-1): z = [h0(t-1)|h1(t-2)] @ wf1 (K=256, regs)
      f32x4 acc[3];
#pragma unroll
      for (int g = 0; g < 3; ++g) acc[g] = (f32x4){bz1r[g], bz1r[g], bz1r[g], bz1r[g]};
#pragma unroll
      for (int kk = 0; kk < 4; ++kk) {
        bf16x8 a = *(const bf16x8*)&A0H[c16][kk * 32 + q8];
#pragma unroll
        for (int g = 0; g < 3; ++g) acc[g] = mfma16(a, wf1[g * 8 + kk], acc[g]);
      }
#pragma unroll
      for (int kk = 0; kk < 4; ++kk) {
        bf16x8 a = *(const bf16x8*)&A1H[c16][kk * 32 + q8];
#pragma unroll
        for (int g = 0; g < 3; ++g) acc[g] = mfma16(a, wf1[g * 8 + 4 + kk], acc[g]);
      }
#pragma unroll
      for (int r = 0; r < 4; ++r) {
        float ht = tanhE(acc[2][r]) + sigmE(acc[0][r]);
        htl1[r] = ht;
        otl1[r] = sigmE(acc[1][r]);
        AT1[q * 4 + r][nc] = (__bf16)ht;
      }
    }
    if (t < 64) {   // L0 gates(t): z = [hist|0|h0(t-1)] @ WB0f (K=160, LDS)
      f32x4 acc[3];
#pragma unroll
      for (int g = 0; g < 3; ++g) acc[g] = (f32x4){bz0r[g], bz0r[g], bz0r[g], bz0r[g]};
      {
        bf16x8 a = *(const bf16x8*)&AH[p][c16][q8];
#pragma unroll
        for (int g = 0; g < 3; ++g)
          acc[g] = mfma16(a, *(const bf16x8*)(WB0 + offW[g]), acc[g]);
      }
#pragma unroll
      for (int kk = 0; kk < 4; ++kk) {
        bf16x8 a = *(const bf16x8*)&A0H[c16][kk * 32 + q8];
#pragma unroll
        for (int g = 0; g < 3; ++g)
          acc[g] = mfma16(a, *(const bf16x8*)(WB0 + offW[g] + (kk + 1) * 512), acc[g]);
      }
#pragma unroll
      for (int r = 0; r < 4; ++r) {
        float ht = tanhE(acc[2][r]) + sigmE(acc[0][r]);
        htl0[r] = ht;
        otl0[r] = sigmE(acc[1][r]);
        AT0[q * 4 + r][nc] = (__bf16)ht;
      }
    }
    __syncthreads();   // B1

    // ================= I2: Wd GEMMs + state updates =================
    if (t < 64) {   // L0 update(t) -> h0(t) into A0H
      float4 drow = *(const float4*)&dmL[sp][0][q * 4];
      float4 mrow = *(const float4*)&dmL[sp][1][q * 4];
      f32x4 accd = (f32x4){bd0r, bd0r, bd0r, bd0r};
#pragma unroll
      for (int kk = 0; kk < 4; ++kk) {
        bf16x8 a = *(const bf16x8*)&AT0[c16][kk * 32 + q8];
        accd = mfma16(a, bwd0[kk], accd);
      }
      float dr[4] = { drow.x, drow.y, drow.z, drow.w };
      float mr[4] = { mrow.x, mrow.y, mrow.z, mrow.w };
#pragma unroll
      for (int r = 0; r < 4; ++r) {
        float hs    = tanhE(accd[r]);
        float dgate = sigmE(__fmaf_rn(dr[r], wt0r, bt0r));
        float hstar = __fmaf_rn(hs, dgate - 1.f, htl0[r]);
        float cn    = tanhE(SCL_T * __fmaf_rn(otl0[r], c0r[r], hstar));
        float hn    = otl0[r] * tanhE(SCL_T * cn);
        float m     = mr[r];
        float hl    = __fmaf_rn(m, hn - h0r[r], h0r[r]);
        float cl    = __fmaf_rn(m, cn - c0r[r], c0r[r]);
        h0r[r] = hl; c0r[r] = cl;
        A0H[q * 4 + r][nc] = (__bf16)hl;
      }
    }
    if (t > 0) {    // L1 update(t-1) -> h1(t-1) into A1H; capture encoded
      float4 dpre = *(const float4*)&dmL[sm][0][q * 4];
      float4 mpre = *(const float4*)&dmL[sm][1][q * 4];
      f32x4 accd = (f32x4){bd1r, bd1r, bd1r, bd1r};
#pragma unroll
      for (int kk = 0; kk < 4; ++kk) {
        bf16x8 a = *(const bf16x8*)&AT1[c16][kk * 32 + q8];
        accd = mfma16(a, bwd1[kk], accd);
      }
      const int tm1 = t - 1;
      float dr[4] = { dpre.x, dpre.y, dpre.z, dpre.w };
      float mr[4] = { mpre.x, mpre.y, mpre.z, mpre.w };
#pragma unroll
      for (int r = 0; r < 4; ++r) {
        float hs    = tanhE(accd[r]);
        float dgate = sigmE(__fmaf_rn(dr[r], wt1r, bt1r));
        float hstar = __fmaf_rn(hs, dgate - 1.f, htl1[r]);
        float cn    = tanhE(SCL_T * __fmaf_rn(otl1[r], c1r[r], hstar));
        float hn    = otl1[r] * tanhE(SCL_T * cn);
        float m     = mr[r];
        float hl    = __fmaf_rn(m, hn - h1r[r], h1r[r]);
        float cl    = __fmaf_rn(m, cn - c1r[r], c1r[r]);
        h1r[r] = hl; c1r[r] = cl;
        A1H[q * 4 + r][nc] = (__bf16)hl;
        if (tm1 == lrow[r]) encr[r] = hl * m;
      }
    }
    // stage t+1 into AH[pn] / dm slot sn (distinct from sp, sm)
    if (tid < 256 && t < 63) {
      AH[pn][srow][scol] = (__bf16)hv;
      if (scol == 5)
        dmL[sn][0][srow] = __fdividef(1.f, __logf(2.7182818284590452f + fmaxf(hv, 0.f)));
      if (scol == 0) dmL[sn][1][srow] = mv;
      if (t < 62) { hv = histrow[(t + 2) * 16]; mv = hmrow[t + 2]; }
    }
    __syncthreads();   // B2
  }

  // ---- decoder head: state = [hist[b,last,:16] | enc128]; LN; FC-ReLU-FC ----
  if (tid < 256)
    stateL[srow][scol] = hist[((long)(b0 + srow) * 64 + lastL[srow]) * 16 + scol];
#pragma unroll
  for (int r = 0; r < 4; ++r)
    stateL[q * 4 + r][16 + nc] = encr[r];
  __syncthreads();

  if (tid < 256) {
    float sm2 = 0.f, sq = 0.f;
    for (int k = scol; k < 144; k += 16) {
      float v = stateL[srow][k];
      sm2 += v; sq += v * v;
    }
    redS[srow][scol] = sm2; redQ[srow][scol] = sq;
  }
  __syncthreads();
  if (tid < 16) {
    float sm2 = 0.f, sq = 0.f;
    for (int s2 = 0; s2 < 16; ++s2) { sm2 += redS[tid][s2]; sq += redQ[tid][s2]; }
    float mu  = sm2 * (1.f / 144.f);
    float var = sq * (1.f / 144.f) - mu * mu;
    redS[0][tid] = mu;
    redQ[0][tid] = rsqrtf(var + 1e-5f);
  }
  __syncthreads();
  if (tid < 256) {
    float mu = redS[0][srow], rs = redQ[0][srow];
    for (int k = scol; k < 144; k += 16)
      stateL[srow][k] = (stateL[srow][k] - mu) * rs * lng[k] + lnb[k];
  }
  __syncthreads();
  if (tid < 256) {
    float accw[8];
#pragma unroll
    for (int o = 0; o < 8; ++o) accw[o] = b1[scol + 16 * o];
    for (int k = 0; k < 144; ++k) {
      float sv = stateL[srow][k];
      const float* w = W1 + k * 128 + scol;
#pragma unroll
      for (int o = 0; o < 8; ++o) accw[o] += sv * w[16 * o];
    }
#pragma unroll
    for (int o = 0; o < 8; ++o) a1L[srow][scol + 16 * o] = fmaxf(accw[o], 0.f);
  }
  __syncthreads();
  for (int e = tid; e < 960; e += 512) {
    int row = e / 60, j = e - row * 60;
    float accv = b2[j];
    for (int k = 0; k < 128; ++k) accv += a1L[row][k] * W2[k * 60 + j];
    accv = (accv != accv) ? 0.f : fminf(fmaxf(accv, -1e4f), 1e4f);  // nan_to_num
    out[(b0 + row) * 60 + j] = accv;
  }
}

extern "C" void kernel_launch(void* const* d_in, const int* in_sizes, int n_in,
                              void* d_out, int out_size, void* d_ws, size_t ws_size,
                              hipStream_t stream) {
  const float* hist  = (const float*)d_in[0];
  const float* hmask = (const float*)d_in[1];
  const float* Wp    = (const float*)d_in[2];
  const float* bp    = (const float*)d_in[3];
  const float* Wx    = (const float*)d_in[4];
  const float* bx    = (const float*)d_in[5];
  const float* Uh    = (const float*)d_in[6];
  const float* Wd    = (const float*)d_in[7];
  const float* bd    = (const float*)d_in[8];
  const float* Wt    = (const float*)d_in[9];
  const float* bt    = (const float*)d_in[10];
  const float* lng   = (const float*)d_in[11];
  const float* lnb   = (const float*)d_in[12];
  const float* W1    = (const float*)d_in[13];
  const float* b1    = (const float*)d_in[14];
  const float* W2    = (const float*)d_in[15];
  const float* b2    = (const float*)d_in[16];
  float* out = (float*)d_out;

  char* ws = (char*)d_ws;
  __bf16* BT0f = (__bf16*)ws;
  __bf16* BWd0 = (__bf16*)(ws + OFF_BWD0);
  __bf16* BT1  = (__bf16*)(ws + OFF_BT1);
  __bf16* BWd1 = (__bf16*)(ws + OFF_BWD1);
  float*  bz0  = (float*)(ws + OFF_BZ0);

  hipFuncSetAttribute((const void*)tlstm_main,
                      hipFuncAttributeMaxDynamicSharedMemorySize, S_TOTAL);

  tlstm_prep<<<730, 256, 0, stream>>>(Wp, bp, Wx, bx, Uh, Wd,
                                      BT0f, BWd0, BT1, BWd1, bz0);
  tlstm_main<<<256, 512, S_TOTAL, stream>>>(hist, hmask, BT0f, BWd0, BT1, BWd1,
                                            bz0, bx, bd, Wt, bt, lng, lnb,
                                            W1, b1, W2, b2, out);
}